// Round 12
// baseline (40.641 us; speedup 1.0000x reference)
//
#include <hip/hip_runtime.h>
#include <cmath>

#define BB 8
#define MM 32
#define CC 80
#define AA 65536    // GRID*GRID*4
#define NBLK 2048   // blocks: 8 batches x 256; each block does 4 chunks of 64 rows
#define NCHUNK 4

__device__ __forceinline__ float fast_rcp(float x)  { return __builtin_amdgcn_rcpf(x); }
__device__ __forceinline__ float fast_log2(float x) { return __builtin_amdgcn_logf(x); }
#define LN2F 0.69314718055994531f

// 4 lanes per row; 256 threads = 64 rows per chunk; 4 chunks per block (same batch).
// 2048 blocks = 8 blocks/CU -> whole grid resident in one occupancy generation.
// Loss elem (t=0): softplus(l)*sigmoid(l)^2 = ln2*log2(1+e^l)*p^2, accumulated in log2 units.
__global__ __launch_bounds__(256) void det_main(
    const float* __restrict__ logits,
    const float* __restrict__ anchors,
    const float* __restrict__ boxes,
    const int* __restrict__ labels_idx,
    float* __restrict__ out,   // [0]=loss (finalize), [1..B*A]=conf, [1+B*A..]=argmax(as float)
    float* __restrict__ ws)    // ws[blk]=loss partial, ws[NBLK+blk]=count partial
{
    __shared__ float4 s_box4[MM];
    __shared__ float  s_area[MM];
    __shared__ int    s_lab[MM];
    __shared__ float  s_part[4 * 2];

    const int tid = threadIdx.x;
    const int j   = tid & 3;                 // lane-in-row
    const int b   = blockIdx.x >> 8;         // 256 blocks per batch
    const int c0  = blockIdx.x & 255;        // base chunk within batch

    if (tid < MM) {
        const float4 bx = ((const float4*)boxes)[b * MM + tid];
        s_box4[tid] = bx;
        s_area[tid] = (bx.z - bx.x) * (bx.w - bx.y);
        s_lab[tid]  = labels_idx[b * MM + tid];
    }
    __syncthreads();

    float accl = 0.0f;   // per-thread accumulators across chunks (valid on j==0)
    float accc = 0.0f;

    #pragma unroll 1
    for (int k = 0; k < NCHUNK; ++k) {
        const int a = ((c0 + (k << 8)) << 6) | (tid >> 2);   // row within batch

        // ---- row loads up-front (each 4-lane cluster covers one 64B line) ----
        const float4* row = (const float4*)(logits + ((size_t)b * AA + (size_t)a) * CC);
        const float4 v0 = row[ 0 + j];
        const float4 v1 = row[ 4 + j];
        const float4 v2 = row[ 8 + j];
        const float4 v3 = row[12 + j];
        const float4 v4 = row[16 + j];
        const float4 anc = ((const float4*)anchors)[a];

        // ---- IoU, division-free; 8 boxes/lane, exact first-max across the group ----
        const float area_a = (anc.z - anc.x) * (anc.w - anc.y);
        float bi = -1.0f, bu = 1.0f;
        int   assign = MM;
        #pragma unroll
        for (int mi = 0; mi < 8; ++mi) {
            const int m = j * 8 + mi;
            const float4 bx = s_box4[m];
            const float w = fmaxf(fminf(anc.z, bx.z) - fmaxf(anc.x, bx.x), 0.0f);
            const float h = fmaxf(fminf(anc.w, bx.w) - fmaxf(anc.y, bx.y), 0.0f);
            const float inter = w * h;
            const float uni = area_a + s_area[m] - inter;
            const bool gt = inter * bu > bi * uni;
            bi = gt ? inter : bi;
            bu = gt ? uni : bu;
            assign = gt ? m : assign;
        }
        #pragma unroll
        for (int off = 1; off <= 2; off <<= 1) {
            const float o_bi = __shfl_xor(bi, off, 64);
            const float o_bu = __shfl_xor(bu, off, 64);
            const int   o_as = __shfl_xor(assign, off, 64);
            const float lhs = o_bi * bu, rhs = bi * o_bu;
            if (lhs > rhs || (lhs == rhs && o_as < assign)) { bi = o_bi; bu = o_bu; assign = o_as; }
        }
        const bool pos     = (bi + bi) >= bu;        // iou >= 0.5
        const bool neg     = bi < 0.1f * bu;         // iou <  0.1
        const bool labeled = pos || neg;
        const int  tc      = pos ? s_lab[assign] : -1;

        // ---- per-lane: 20 logits: max/argmax + sum log2(1+u)*p^2 ----
        float mx   = -INFINITY;
        int   amx  = CC;
        float lsum = 0.0f;

#define PROC4(V, KBASE)                                                        \
        {                                                                      \
            const float lv[4] = {(V).x, (V).y, (V).z, (V).w};                  \
            _Pragma("unroll")                                                  \
            for (int jj = 0; jj < 4; ++jj) {                                   \
                const int c = (KBASE) * 16 + j * 4 + jj;                       \
                const float l = lv[jj];                                        \
                const bool gt = l > mx;                                        \
                mx  = gt ? l : mx;                                             \
                amx = gt ? c : amx;                                            \
                const float u  = __expf(l);                                    \
                const float w  = 1.0f + u;                                     \
                const float lg = fast_log2(w);                                 \
                const float r  = fast_rcp(w);                                  \
                const float p  = u * r;                                        \
                lsum = fmaf(lg * p, p, lsum);                                  \
            }                                                                  \
        }

        PROC4(v0, 0)
        PROC4(v1, 1)
        PROC4(v2, 2)
        PROC4(v3, 3)
        PROC4(v4, 4)
#undef PROC4

        float loss = LN2F * lsum;

        // ---- target-class correction: lane 0 of a positive row re-loads logits[tc] ----
        if (tc >= 0 && j == 0) {
            const float l_tc = logits[((size_t)b * AA + (size_t)a) * CC + tc];
            const float u  = __expf(l_tc);
            const float w  = 1.0f + u;
            const float bce0 = LN2F * fast_log2(w);   // softplus(l_tc)
            const float r  = fast_rcp(w);
            const float p  = u * r;
            const float bce1 = bce0 - l_tc;
            const float d1   = 1.0f - p;
            loss += bce1 * d1 * d1 - bce0 * p * p;
        }

        // ---- group reduce (4 lanes): loss sum, max/argmax with first-index ties ----
        #pragma unroll
        for (int off = 1; off <= 2; off <<= 1) {
            loss += __shfl_xor(loss, off, 64);
            const float o_mx  = __shfl_xor(mx,  off, 64);
            const int   o_amx = __shfl_xor(amx, off, 64);
            if (o_mx > mx || (o_mx == mx && o_amx < amx)) { mx = o_mx; amx = o_amx; }
        }

        // ---- per-row outputs + per-thread accumulation (lane j==0) ----
        if (j == 0) {
            const size_t ba = (size_t)b * AA + (size_t)a;
            const float u = __expf(mx);
            out[1 + ba] = u * fast_rcp(1.0f + u);     // sigmoid(max logit) == max prob
            out[1 + (size_t)BB * AA + ba] = (float)amx;
            accl += labeled ? loss : 0.0f;
            accc += pos ? 1.0f : 0.0f;
        }
    }

    // ---- single block reduce of the chunk-accumulated {loss, count} ----
    float rl = accl;
    float rc = accc;
    #pragma unroll
    for (int off = 4; off <= 32; off <<= 1) {
        rl += __shfl_xor(rl, off, 64);
        rc += __shfl_xor(rc, off, 64);
    }
    {
        const float rl1 = __shfl_xor(rl, 1, 64);   // fold lanes 1,2,3 partials (j!=0 are zero
        const float rc1 = __shfl_xor(rc, 1, 64);   //  already, but shuffles above mixed 4..32
        rl += rl1; rc += rc1;                       //  only; fold off=1,2 now)
        const float rl2 = __shfl_xor(rl, 2, 64);
        const float rc2 = __shfl_xor(rc, 2, 64);
        rl += rl2; rc += rc2;
    }
    const int wave = tid >> 6;
    if ((tid & 63) == 0) { s_part[wave * 2] = rl; s_part[wave * 2 + 1] = rc; }
    __syncthreads();
    if (tid == 0) {
        ws[blockIdx.x]        = s_part[0] + s_part[2] + s_part[4] + s_part[6];
        ws[NBLK + blockIdx.x] = s_part[1] + s_part[3] + s_part[5] + s_part[7];
    }
}

__global__ __launch_bounds__(1024) void det_final(const float* __restrict__ ws, float* __restrict__ out) {
    __shared__ float s_l[16];
    __shared__ float s_c[16];
    const int tid = threadIdx.x;
    float l = 0.0f, c = 0.0f;
    #pragma unroll
    for (int i = tid; i < NBLK; i += 1024) {
        l += ws[i];
        c += ws[NBLK + i];
    }
    #pragma unroll
    for (int off = 32; off > 0; off >>= 1) {
        l += __shfl_down(l, off, 64);
        c += __shfl_down(c, off, 64);
    }
    const int wave = tid >> 6;
    if ((tid & 63) == 0) { s_l[wave] = l; s_c[wave] = c; }
    __syncthreads();
    if (tid == 0) {
        float tl = 0.0f, tcnt = 0.0f;
        #pragma unroll
        for (int w = 0; w < 16; ++w) { tl += s_l[w]; tcnt += s_c[w]; }
        out[0] = tl / tcnt;
    }
}

extern "C" void kernel_launch(void* const* d_in, const int* in_sizes, int n_in,
                              void* d_out, int out_size, void* d_ws, size_t ws_size,
                              hipStream_t stream) {
    const float* logits     = (const float*)d_in[0];
    const float* anchors    = (const float*)d_in[1];
    const float* boxes      = (const float*)d_in[2];
    // d_in[3] (one-hot labels) unused: gather(labels, assign) == one_hot(labels_idx[assign])
    const int*   labels_idx = (const int*)d_in[4];
    float* out = (float*)d_out;
    float* ws  = (float*)d_ws;

    det_main<<<dim3(NBLK), dim3(256), 0, stream>>>(logits, anchors, boxes, labels_idx, out, ws);
    det_final<<<1, 1024, 0, stream>>>(ws, out);
}

// Round 13
// 36.090 us; speedup vs baseline: 1.1261x; 1.1261x over previous
//
#include <hip/hip_runtime.h>
#include <cmath>

#define BB 8
#define MM 32
#define CC 80
#define AA 65536   // GRID*GRID*4
#define NBLK 8192  // (BB*AA*4 lanes)/256

__device__ __forceinline__ float fast_rcp(float x)  { return __builtin_amdgcn_rcpf(x); }
__device__ __forceinline__ float fast_log2(float x) { return __builtin_amdgcn_logf(x); }
#define LN2F 0.69314718055994531f

// 4 lanes per row; 256 threads = 64 rows per block; 8192 blocks.
// Loss elem (t=0): softplus(l)*sigmoid(l)^2 = ln2*log2(1+e^l)*p^2, accumulated in log2 units.
// Target-class correction: lane 0 of a positive row re-loads logits[tc] from global
// (rare; L2-warm; avoids per-element compare AND runtime register indexing/scratch).
__global__ __launch_bounds__(256) void det_main(
    const float* __restrict__ logits,
    const float* __restrict__ anchors,
    const float* __restrict__ boxes,
    const int* __restrict__ labels_idx,
    float* __restrict__ out,   // [0]=loss (finalize), [1..B*A]=conf, [1+B*A..]=argmax(as float)
    float* __restrict__ ws)    // ws[blk]=loss partial, ws[NBLK+blk]=count partial
{
    __shared__ float4 s_box4[MM];
    __shared__ float  s_area[MM];
    __shared__ int    s_lab[MM];
    __shared__ float  s_part[4 * 2];

    const int tid = threadIdx.x;
    const int j   = tid & 3;                                  // lane-in-row
    const int b   = blockIdx.x >> 10;                         // 1024 blocks per batch
    const int a   = ((blockIdx.x & 1023) << 6) | (tid >> 2);  // row within batch

    if (tid < MM) {
        const float4 bx = ((const float4*)boxes)[b * MM + tid];
        s_box4[tid] = bx;
        s_area[tid] = (bx.z - bx.x) * (bx.w - bx.y);
        s_lab[tid]  = labels_idx[b * MM + tid];
    }
    __syncthreads();

    // ---- row loads up-front (each 4-lane cluster covers one 64B line) ----
    const float4* row = (const float4*)(logits + ((size_t)b * AA + (size_t)a) * CC);
    const float4 v0 = row[ 0 + j];
    const float4 v1 = row[ 4 + j];
    const float4 v2 = row[ 8 + j];
    const float4 v3 = row[12 + j];
    const float4 v4 = row[16 + j];
    const float4 anc = ((const float4*)anchors)[a];

    // ---- IoU, division-free; 8 boxes/lane, exact first-max across the 4-lane group ----
    const float area_a = (anc.z - anc.x) * (anc.w - anc.y);
    float bi = -1.0f, bu = 1.0f;
    int   assign = MM;
    #pragma unroll
    for (int mi = 0; mi < 8; ++mi) {
        const int m = j * 8 + mi;
        const float4 bx = s_box4[m];
        const float w = fmaxf(fminf(anc.z, bx.z) - fmaxf(anc.x, bx.x), 0.0f);
        const float h = fmaxf(fminf(anc.w, bx.w) - fmaxf(anc.y, bx.y), 0.0f);
        const float inter = w * h;
        const float uni = area_a + s_area[m] - inter;
        const bool gt = inter * bu > bi * uni;
        bi = gt ? inter : bi;
        bu = gt ? uni : bu;
        assign = gt ? m : assign;
    }
    #pragma unroll
    for (int off = 1; off <= 2; off <<= 1) {
        const float o_bi = __shfl_xor(bi, off, 64);
        const float o_bu = __shfl_xor(bu, off, 64);
        const int   o_as = __shfl_xor(assign, off, 64);
        const float lhs = o_bi * bu, rhs = bi * o_bu;
        if (lhs > rhs || (lhs == rhs && o_as < assign)) { bi = o_bi; bu = o_bu; assign = o_as; }
    }
    const bool pos     = (bi + bi) >= bu;        // iou >= 0.5
    const bool neg     = bi < 0.1f * bu;         // iou <  0.1
    const bool labeled = pos || neg;
    const int  tc      = pos ? s_lab[assign] : -1;

    // ---- per-lane: 20 logits (c = k*16 + j*4 + jj): max/argmax + sum log2(1+u)*p^2 ----
    float mx   = -INFINITY;
    int   amx  = CC;
    float lsum = 0.0f;

#define PROC4(V, KBASE)                                                        \
    {                                                                          \
        const float lv[4] = {(V).x, (V).y, (V).z, (V).w};                      \
        _Pragma("unroll")                                                      \
        for (int jj = 0; jj < 4; ++jj) {                                       \
            const int c = (KBASE) * 16 + j * 4 + jj;                           \
            const float l = lv[jj];                                            \
            const bool gt = l > mx;                                            \
            mx  = gt ? l : mx;                                                 \
            amx = gt ? c : amx;                                                \
            const float u  = __expf(l);                                        \
            const float w  = 1.0f + u;                                         \
            const float lg = fast_log2(w);                                     \
            const float r  = fast_rcp(w);                                      \
            const float p  = u * r;                                            \
            lsum = fmaf(lg * p, p, lsum);                                      \
        }                                                                      \
    }

    PROC4(v0, 0)
    PROC4(v1, 1)
    PROC4(v2, 2)
    PROC4(v3, 3)
    PROC4(v4, 4)
#undef PROC4

    float loss = LN2F * lsum;

    // ---- target-class correction: lane 0 of a positive row re-loads logits[tc] ----
    // Rare (positives only): one scattered 4B load, L2/L3-warm, no register indexing.
    if (tc >= 0 && j == 0) {
        const float l_tc = logits[((size_t)b * AA + (size_t)a) * CC + tc];
        const float u  = __expf(l_tc);
        const float w  = 1.0f + u;
        const float bce0 = LN2F * fast_log2(w);   // softplus(l_tc)
        const float r  = fast_rcp(w);
        const float p  = u * r;
        const float bce1 = bce0 - l_tc;
        const float d1   = 1.0f - p;
        loss += bce1 * d1 * d1 - bce0 * p * p;
    }

    // ---- group reduce (4 lanes): loss sum, max/argmax with first-index ties ----
    #pragma unroll
    for (int off = 1; off <= 2; off <<= 1) {
        loss += __shfl_xor(loss, off, 64);
        const float o_mx  = __shfl_xor(mx,  off, 64);
        const int   o_amx = __shfl_xor(amx, off, 64);
        if (o_mx > mx || (o_mx == mx && o_amx < amx)) { mx = o_mx; amx = o_amx; }
    }

    // ---- per-row outputs (lane j==0) ----
    if (j == 0) {
        const size_t ba = (size_t)b * AA + (size_t)a;
        const float u = __expf(mx);
        out[1 + ba] = u * fast_rcp(1.0f + u);     // sigmoid(max logit) == max prob
        out[1 + (size_t)BB * AA + ba] = (float)amx;
    }

    // ---- wave reduce {labeled loss, pos count} over the 16 groups ----
    float rl = (j == 0 && labeled) ? loss : 0.0f;
    float rc = (j == 0 && pos) ? 1.0f : 0.0f;
    #pragma unroll
    for (int off = 4; off <= 32; off <<= 1) {
        rl += __shfl_xor(rl, off, 64);
        rc += __shfl_xor(rc, off, 64);
    }
    const int wave = tid >> 6;
    if ((tid & 63) == 0) { s_part[wave * 2] = rl; s_part[wave * 2 + 1] = rc; }
    __syncthreads();
    if (tid == 0) {
        ws[blockIdx.x]        = s_part[0] + s_part[2] + s_part[4] + s_part[6];
        ws[NBLK + blockIdx.x] = s_part[1] + s_part[3] + s_part[5] + s_part[7];
    }
}

__global__ __launch_bounds__(1024) void det_final(const float* __restrict__ ws, float* __restrict__ out) {
    __shared__ float s_l[16];
    __shared__ float s_c[16];
    const int tid = threadIdx.x;
    float l = 0.0f, c = 0.0f;
    #pragma unroll
    for (int i = tid; i < NBLK; i += 1024) {
        l += ws[i];
        c += ws[NBLK + i];
    }
    #pragma unroll
    for (int off = 32; off > 0; off >>= 1) {
        l += __shfl_down(l, off, 64);
        c += __shfl_down(c, off, 64);
    }
    const int wave = tid >> 6;
    if ((tid & 63) == 0) { s_l[wave] = l; s_c[wave] = c; }
    __syncthreads();
    if (tid == 0) {
        float tl = 0.0f, tcnt = 0.0f;
        #pragma unroll
        for (int w = 0; w < 16; ++w) { tl += s_l[w]; tcnt += s_c[w]; }
        out[0] = tl / tcnt;
    }
}

extern "C" void kernel_launch(void* const* d_in, const int* in_sizes, int n_in,
                              void* d_out, int out_size, void* d_ws, size_t ws_size,
                              hipStream_t stream) {
    const float* logits     = (const float*)d_in[0];
    const float* anchors    = (const float*)d_in[1];
    const float* boxes      = (const float*)d_in[2];
    // d_in[3] (one-hot labels) unused: gather(labels, assign) == one_hot(labels_idx[assign])
    const int*   labels_idx = (const int*)d_in[4];
    float* out = (float*)d_out;
    float* ws  = (float*)d_ws;

    det_main<<<dim3(NBLK), dim3(256), 0, stream>>>(logits, anchors, boxes, labels_idx, out, ws);
    det_final<<<1, 1024, 0, stream>>>(ws, out);
}